// Round 17
// baseline (248.218 us; speedup 1.0000x reference)
//
#include <hip/hip_runtime.h>

#define NEG_SLOPE 0.2f
#define BK_SH 8              // 256 dst nodes per bucket
#define BK_SZ 256
#define MAXBUCK 512          // N=100000 -> 391 buckets
#define EPB 8192             // edges per binning block

typedef _Float16 half8 __attribute__((ext_vector_type(8)));
typedef float f32x4 __attribute__((ext_vector_type(4)));

// ---------------------------------------------------------------------------
// k_castW: W[k][f] (Kx32 f32) -> Wt[f][k] (32xK fp16)
// ---------------------------------------------------------------------------
__global__ __launch_bounds__(256) void k_castW(const float* __restrict__ W,
                                               _Float16* __restrict__ Wt,
                                               int K) {
  for (int i = threadIdx.x; i < K * 32; i += 256) {
    int k = i >> 5, f = i & 31;
    Wt[f * K + k] = (_Float16)W[i];
  }
}

// ---------------------------------------------------------------------------
// k_feat1: H = x @ W1 (f32 input read directly, cast to fp16 in-register),
// mfma_f32_16x16x32_f16, fused as_/ad_ scores. One wave = 16 nodes.
// ---------------------------------------------------------------------------
__global__ __launch_bounds__(256) void k_feat1(
    const float* __restrict__ x, const _Float16* __restrict__ Wt,
    const float* __restrict__ a_src, const float* __restrict__ a_dst,
    _Float16* __restrict__ Hh, float* __restrict__ as_, float* __restrict__ ad_,
    int N) {
  int w = threadIdx.x >> 6;
  int lane = threadIdx.x & 63;
  int base = (blockIdx.x * 4 + w) * 16;
  if (base >= N) return;
  int row16 = lane & 15;
  int kg = lane >> 4;  // 0..3
  f32x4 acc0 = {0.f, 0.f, 0.f, 0.f};
  f32x4 acc1 = {0.f, 0.f, 0.f, 0.f};
  const float* xr = x + (size_t)(base + row16) * 128 + kg * 8;
#pragma unroll
  for (int kt = 0; kt < 4; ++kt) {
    float4 u0 = *reinterpret_cast<const float4*>(xr + kt * 32);
    float4 u1 = *reinterpret_cast<const float4*>(xr + kt * 32 + 4);
    half8 a;
    a[0] = (_Float16)u0.x; a[1] = (_Float16)u0.y;
    a[2] = (_Float16)u0.z; a[3] = (_Float16)u0.w;
    a[4] = (_Float16)u1.x; a[5] = (_Float16)u1.y;
    a[6] = (_Float16)u1.z; a[7] = (_Float16)u1.w;
    half8 b0 = *reinterpret_cast<const half8*>(Wt + (size_t)row16 * 128 +
                                               kt * 32 + kg * 8);
    half8 b1 = *reinterpret_cast<const half8*>(Wt + (size_t)(16 + row16) * 128 +
                                               kt * 32 + kg * 8);
    acc0 = __builtin_amdgcn_mfma_f32_16x16x32_f16(a, b0, acc0, 0, 0, 0);
    acc1 = __builtin_amdgcn_mfma_f32_16x16x32_f16(a, b1, acc1, 0, 0, 0);
  }
  float aS0 = a_src[row16], aS1 = a_src[16 + row16];
  float aD0 = a_dst[row16], aD1 = a_dst[16 + row16];
  float tS[4], tD[4];
#pragma unroll
  for (int r = 0; r < 4; ++r) {
    int row = base + kg * 4 + r;
    Hh[(size_t)row * 32 + row16] = (_Float16)acc0[r];
    Hh[(size_t)row * 32 + 16 + row16] = (_Float16)acc1[r];
    tS[r] = acc0[r] * aS0 + acc1[r] * aS1;
    tD[r] = acc0[r] * aD0 + acc1[r] * aD1;
  }
#pragma unroll
  for (int off = 1; off <= 8; off <<= 1) {
#pragma unroll
    for (int r = 0; r < 4; ++r) {
      tS[r] += __shfl_xor(tS[r], off, 64);
      tD[r] += __shfl_xor(tD[r], off, 64);
    }
  }
  if (row16 == 0) {
#pragma unroll
    for (int r = 0; r < 4; ++r) {
      as_[base + kg * 4 + r] = tS[r];
      ad_[base + kg * 4 + r] = tD[r];
    }
  }
}

// ---------------------------------------------------------------------------
// CSR build: single-pass bucketed counting sort (R16 structure).
// ---------------------------------------------------------------------------
__global__ __launch_bounds__(256) void k_zero(int* __restrict__ p, int n) {
  int i = blockIdx.x * 256 + threadIdx.x;
  if (i < n) p[i] = 0;
}

__global__ __launch_bounds__(256) void k_bhist(const int* __restrict__ ei,
                                               int E, int* __restrict__ bcnt,
                                               int* __restrict__ hmatT,
                                               int nb, int nbuck) {
  __shared__ int h[MAXBUCK];
  for (int i = threadIdx.x; i < nbuck; i += 256) h[i] = 0;
  __syncthreads();
  long base = (long)blockIdx.x * EPB;
#pragma unroll 4
  for (int i = 0; i < EPB / 256; ++i) {
    long e = base + i * 256 + threadIdx.x;
    if (e < E) atomicAdd(&h[ei[E + e] >> BK_SH], 1);
  }
  __syncthreads();
  for (int i = threadIdx.x; i < nbuck; i += 256) {
    hmatT[(size_t)i * nb + blockIdx.x] = h[i];
    if (h[i]) atomicAdd(&bcnt[i], h[i]);
  }
}

__global__ __launch_bounds__(1024) void k_scan(const int* __restrict__ bcnt,
                                               int* __restrict__ boff,
                                               int* __restrict__ ptr, int nbuck,
                                               int N, int E) {
  __shared__ int s[1024];
  int t = threadIdx.x;
  int v = (t < nbuck) ? bcnt[t] : 0;
  s[t] = v;
  __syncthreads();
  for (int off = 1; off < 1024; off <<= 1) {
    int x = (t >= off) ? s[t - off] : 0;
    __syncthreads();
    s[t] += x;
    __syncthreads();
  }
  if (t < nbuck) boff[t] = s[t] - v;
  if (t == 0) {
    boff[nbuck] = E;
    ptr[N] = E;
  }
}

// one wave per bucket: prefix-scan that bucket's per-block counts (contiguous)
__global__ __launch_bounds__(256) void k_colscan(const int* __restrict__ hmatT,
                                                 int* __restrict__ lbgT,
                                                 const int* __restrict__ boff,
                                                 int nb, int nbuck) {
  int wid = (blockIdx.x * 256 + threadIdx.x) >> 6;  // bucket
  int lane = threadIdx.x & 63;
  if (wid >= nbuck) return;
  const int* row = hmatT + (size_t)wid * nb;
  int* orow = lbgT + (size_t)wid * nb;
  int base = boff[wid];
  for (int c = 0; c < nb; c += 64) {
    int v = (c + lane < nb) ? row[c + lane] : 0;
    int s = v;
#pragma unroll
    for (int off = 1; off < 64; off <<= 1) {
      int x = __shfl_up(s, off, 64);
      if (lane >= off) s += x;
    }
    if (c + lane < nb) orow[c + lane] = base + s - v;
    base += __shfl(s, 63, 64);
  }
}

// phase A: single-pass LDS-staged binning with bucket-sorted coalesced flush.
__global__ __launch_bounds__(256) void k_binA(
    const int* __restrict__ ei, int E, const int* __restrict__ hmatT,
    const int* __restrict__ lbgT, unsigned* __restrict__ packed, int nb,
    int nbuck) {
  __shared__ int h[MAXBUCK];
  __shared__ int lbase[MAXBUCK];
  __shared__ int lb[MAXBUCK];
  __shared__ int cur[MAXBUCK];
  __shared__ int psum[256];
  __shared__ unsigned rec[EPB];
  __shared__ unsigned char bkt[EPB];
  int t = threadIdx.x;
  for (int i = t; i < MAXBUCK; i += 256) {
    h[i] = (i < nbuck) ? hmatT[(size_t)i * nb + blockIdx.x] : 0;
    lbase[i] = (i < nbuck) ? lbgT[(size_t)i * nb + blockIdx.x] : 0;
  }
  __syncthreads();
  long base = (long)blockIdx.x * EPB;
  int cnt = (int)((E - base) < EPB ? (E - base) : EPB);
  int a0 = h[2 * t], a1 = h[2 * t + 1];
  psum[t] = a0 + a1;
  __syncthreads();
  for (int off = 1; off < 256; off <<= 1) {
    int x = (t >= off) ? psum[t - off] : 0;
    __syncthreads();
    psum[t] += x;
    __syncthreads();
  }
  int pex = psum[t] - (a0 + a1);
  lb[2 * t] = pex;
  lb[2 * t + 1] = pex + a0;
  cur[2 * t] = pex;
  cur[2 * t + 1] = pex + a0;
  __syncthreads();
#pragma unroll 4
  for (int i = 0; i < EPB / 256; ++i) {
    int e = i * 256 + t;
    if (e < cnt) {
      int s = ei[base + e], d = ei[E + base + e];
      int b = d >> BK_SH;
      int pos = atomicAdd(&cur[b], 1);
      rec[pos] = ((unsigned)s << 8) | (unsigned)(d & (BK_SZ - 1));
      bkt[pos] = (unsigned char)b;
    }
  }
  __syncthreads();
  for (int i = t; i < cnt; i += 256) {
    int b0 = bkt[i];
    int b = (i >= lb[b0] && i < cur[b0]) ? b0 : b0 + 256;
    packed[(size_t)lbase[b] + (i - lb[b])] = rec[i];
  }
}

// phase B: one block per bucket; node-level CSR ptr via LDS hist+scan.
__global__ __launch_bounds__(256) void k_binB(const unsigned* __restrict__ packed,
                                              const int* __restrict__ boff,
                                              int* __restrict__ ptr,
                                              int* __restrict__ srcs, int N) {
  int b = blockIdx.x;
  int beg = boff[b], end = boff[b + 1];
  int t = threadIdx.x;
  __shared__ int lcnt[BK_SZ];
  __shared__ int sc[BK_SZ];
  __shared__ int lcur[BK_SZ];
  lcnt[t] = 0;
  __syncthreads();
  for (int i = beg + t; i < end; i += 256)
    atomicAdd(&lcnt[packed[i] & (BK_SZ - 1)], 1);
  __syncthreads();
  int v = lcnt[t];
  sc[t] = v;
  __syncthreads();
  for (int off = 1; off < 256; off <<= 1) {
    int x = (t >= off) ? sc[t - off] : 0;
    __syncthreads();
    sc[t] += x;
    __syncthreads();
  }
  int excl = sc[t] - v;
  int node = (b << BK_SH) + t;
  if (node < N) ptr[node] = beg + excl;
  lcur[t] = excl;
  __syncthreads();
  for (int i = beg + t; i < end; i += 256) {
    unsigned p = packed[i];
    int slot = atomicAdd(&lcur[p & (BK_SZ - 1)], 1);
    srcs[(size_t)beg + slot] = (int)(p >> 8);
  }
}

// ---------------------------------------------------------------------------
// k_fill: rec[e] = (srcs[e], as_[srcs[e]])  — streaming, off critical path.
// ---------------------------------------------------------------------------
__global__ __launch_bounds__(256) void k_fill(const int* __restrict__ srcs,
                                              const float* __restrict__ as_,
                                              int2* __restrict__ rec, int E) {
  int i = blockIdx.x * 256 + threadIdx.x;
  int stride = gridDim.x * 256;
  for (int e = i; e < E; e += stride) {
    int s = srcs[e];
    int2 r;
    r.x = s;
    r.y = __float_as_int(as_[s]);
    rec[e] = r;
  }
}

// ---------------------------------------------------------------------------
// k_gatherT: 32 lanes/node = 8 edge-slots x 4 feature-lanes (half8 = 16B).
// 2-deep pipeline; 8B (src,score) records -> ONE divergent load per edge.
// MODE=0: fused layer-2 feature transform: Hh2 = relu(row)@W2 (+as2/ad2)
// MODE=1: out(f32) = relu(row) @ Wf + bf   (fused final linear)
// ---------------------------------------------------------------------------
template <int MODE>
__global__ __launch_bounds__(256) void k_gatherT(
    const int* __restrict__ ptr, const int2* __restrict__ rec,
    const _Float16* __restrict__ Hh, const float* __restrict__ as_,
    const float* __restrict__ ad_, const float* __restrict__ b,
    const float* __restrict__ Wx, const float* __restrict__ aS2p,
    const float* __restrict__ aD2p, const float* __restrict__ bfp,
    _Float16* __restrict__ Hh2, float* __restrict__ as2v,
    float* __restrict__ ad2v, float* __restrict__ OUT, int N) {
  __shared__ float sW[32 * 32];
  __shared__ float sO[8][33];
  for (int i = threadIdx.x; i < 32 * 32; i += 256) sW[i] = Wx[i];
  int g = threadIdx.x >> 5;
  int lane = threadIdx.x & 31;
  int sub = lane >> 2;  // edge slot 0..7
  int q = lane & 3;     // feature block of 8
  int d = blockIdx.x * 8 + g;
  int dc = d < N ? d : N - 1;
  float ad_d = ad_[dc];
  float acc[8] = {0.f, 0.f, 0.f, 0.f, 0.f, 0.f, 0.f, 0.f};
  float sumw = 0.f;
  int beg = ptr[dc], end = ptr[dc + 1];
  // prefetch batches 0 and 1
  bool v0 = sub < end - beg;
  int2 r0 = v0 ? rec[beg + sub] : make_int2(dc, 0);
  half8 hv0 = *reinterpret_cast<const half8*>(Hh + (size_t)r0.x * 32 + q * 8);
  bool v1 = sub < end - (beg + 8);
  int2 r1 = v1 ? rec[beg + 8 + sub] : make_int2(dc, 0);
  half8 hv1 = *reinterpret_cast<const half8*>(Hh + (size_t)r1.x * 32 + q * 8);
  int nb8 = (end - beg + 7) >> 3;
  int j = beg;
#pragma unroll 2
  for (int it = 0; it < nb8; ++it) {
    // prefetch batch n+2
    int jn = j + 16;
    bool v2 = sub < end - jn;
    int2 r2 = v2 ? rec[jn + sub] : make_int2(dc, 0);
    half8 hv2 = *reinterpret_cast<const half8*>(Hh + (size_t)r2.x * 32 + q * 8);
    // consume batch n
    float sc2 = __int_as_float(r0.y) + ad_d;
    float el = sc2 > 0.f ? sc2 : NEG_SLOPE * sc2;
    float w = v0 ? __expf(el) : 0.f;
#pragma unroll
    for (int i = 0; i < 8; ++i) acc[i] += w * (float)hv0[i];
    sumw += w;
    j = jn - 8;
    v0 = v1; r0 = r1; hv0 = hv1;
    v1 = v2; r1 = r2; hv1 = hv2;
  }
#pragma unroll
  for (int off = 4; off <= 16; off <<= 1) {
#pragma unroll
    for (int i = 0; i < 8; ++i) acc[i] += __shfl_xor(acc[i], off, 32);
    sumw += __shfl_xor(sumw, off, 32);
  }
  if (sub == 0) {
    // self-loop
    float s0 = as_[dc] + ad_d;
    float e0 = s0 > 0.f ? s0 : NEG_SLOPE * s0;
    float w0 = __expf(e0);
    half8 hs = *reinterpret_cast<const half8*>(Hh + (size_t)dc * 32 + q * 8);
#pragma unroll
    for (int i = 0; i < 8; ++i) acc[i] += w0 * (float)hs[i];
    sumw += w0;
    float inv = 1.f / (sumw + 1e-16f);
#pragma unroll
    for (int i = 0; i < 8; ++i)
      sO[g][q * 8 + i] = fmaxf(acc[i] * inv + b[q * 8 + i], 0.f);
  }
  __syncthreads();
  // epilogue GEMM: row (LDS) @ Wx -> 32 outputs per group
  float accf = (MODE == 1) ? bfp[lane] : 0.f;
#pragma unroll
  for (int k = 0; k < 32; ++k) accf += sO[g][k] * sW[k * 32 + lane];
  if (MODE == 1) {
    if (d < N) OUT[(size_t)d * 32 + lane] = accf;
  } else {
    if (d < N) Hh2[(size_t)d * 32 + lane] = (_Float16)accf;
    float vs = accf * aS2p[lane];
    float vd = accf * aD2p[lane];
#pragma unroll
    for (int off = 1; off < 32; off <<= 1) {
      vs += __shfl_xor(vs, off, 32);
      vd += __shfl_xor(vd, off, 32);
    }
    if (lane == 0 && d < N) {
      as2v[d] = vs;
      ad2v[d] = vd;
    }
  }
}

extern "C" void kernel_launch(void* const* d_in, const int* in_sizes, int n_in,
                              void* d_out, int out_size, void* d_ws,
                              size_t ws_size, hipStream_t stream) {
  const float* x = (const float*)d_in[0];
  const int* ei = (const int*)d_in[1];
  const float* W1 = (const float*)d_in[2];
  const float* as1 = (const float*)d_in[3];
  const float* ad1 = (const float*)d_in[4];
  const float* b1 = (const float*)d_in[5];
  const float* W2 = (const float*)d_in[6];
  const float* as2 = (const float*)d_in[7];
  const float* ad2 = (const float*)d_in[8];
  const float* b2 = (const float*)d_in[9];
  const float* Wf = (const float*)d_in[10];
  const float* bf = (const float*)d_in[11];
  float* out = (float*)d_out;

  const int H = in_sizes[3];        // 32
  const int FIN = in_sizes[2] / H;  // 128
  const int N = in_sizes[0] / FIN;  // 100000
  const int E = in_sizes[1] / 2;    // 3200000
  const int nbuck = (N + BK_SZ - 1) >> BK_SH;  // 391
  (void)n_in; (void)out_size; (void)ws_size; (void)H;

  const int nodeBlocks = (N + 7) / 8;
  const int binBlocks = (E + EPB - 1) / EPB;
  const int mfmaBlocks = (N / 16 + 3) / 4;

  // region0 (time-multiplexed): packed E*4 (build) -> rec E*8 (layers)
  size_t r0 = (size_t)E * 8;
  char* basep = (char*)d_ws;
  unsigned* packed = (unsigned*)basep;
  int2* recb = (int2*)basep;
  char* p = basep + r0;
  _Float16* Hh1 = (_Float16*)p;  p += (size_t)N * 32 * 2;
  _Float16* Hh2 = (_Float16*)p;  p += (size_t)N * 32 * 2;
  _Float16* Wt1 = (_Float16*)p;  p += (size_t)128 * 32 * 2;
  float* asv = (float*)p;        p += (size_t)N * 4;
  float* adv = (float*)p;        p += (size_t)N * 4;
  float* asv2 = (float*)p;       p += (size_t)N * 4;
  float* adv2 = (float*)p;       p += (size_t)N * 4;
  int* ptr = (int*)p;            p += (size_t)(N + 1) * 4;
  int* srcs = (int*)p;           p += (size_t)E * 4;
  int* bcnt = (int*)p;           p += (size_t)nbuck * 4;
  int* boff = (int*)p;           p += (size_t)(nbuck + 1) * 4;
  int* hmatT = (int*)p;          p += (size_t)binBlocks * nbuck * 4;
  int* lbgT = (int*)p;

  // ---- build CSR by destination (once; graph is layer-invariant) ----
  k_zero<<<(nbuck + 255) / 256, 256, 0, stream>>>(bcnt, nbuck);
  k_bhist<<<binBlocks, 256, 0, stream>>>(ei, E, bcnt, hmatT, binBlocks, nbuck);
  k_scan<<<1, 1024, 0, stream>>>(bcnt, boff, ptr, nbuck, N, E);
  k_colscan<<<(nbuck * 64 + 255) / 256, 256, 0, stream>>>(hmatT, lbgT, boff,
                                                          binBlocks, nbuck);
  k_binA<<<binBlocks, 256, 0, stream>>>(ei, E, hmatT, lbgT, packed, binBlocks,
                                        nbuck);
  k_binB<<<nbuck, 256, 0, stream>>>(packed, boff, ptr, srcs, N);

  // ---- weights ----
  k_castW<<<1, 256, 0, stream>>>(W1, Wt1, 128);

  // ---- layer 1 ----  (packed dead after binB; region0 becomes rec)
  k_feat1<<<mfmaBlocks, 256, 0, stream>>>(x, Wt1, as1, ad1, Hh1, asv, adv, N);
  k_fill<<<2048, 256, 0, stream>>>(srcs, asv, recb, E);
  // gather1 + fused feat2: reads Hh1/rec, writes Hh2 + as2v/ad2v
  k_gatherT<0><<<nodeBlocks, 256, 0, stream>>>(ptr, recb, Hh1, asv, adv, b1,
                                               W2, as2, ad2, nullptr, Hh2,
                                               asv2, adv2, nullptr, N);

  // ---- layer 2 (final linear fused into gather) ----
  k_fill<<<2048, 256, 0, stream>>>(srcs, asv2, recb, E);
  k_gatherT<1><<<nodeBlocks, 256, 0, stream>>>(ptr, recb, Hh2, asv2, adv2, b2,
                                               Wf, nullptr, nullptr, bf,
                                               nullptr, nullptr, nullptr, out,
                                               N);
}

// Round 18
// 215.702 us; speedup vs baseline: 1.1507x; 1.1507x over previous
//
#include <hip/hip_runtime.h>

#define NEG_SLOPE 0.2f
#define BK_SH 8              // 256 dst nodes per bucket
#define BK_SZ 256
#define MAXBUCK 512          // N=100000 -> 391 buckets
#define EPB 8192             // edges per binning block

typedef _Float16 half8 __attribute__((ext_vector_type(8)));
typedef _Float16 h2 __attribute__((ext_vector_type(2)));
typedef float f32x4 __attribute__((ext_vector_type(4)));

// ---------------------------------------------------------------------------
// k_castW: W[k][f] (Kx32 f32) -> Wt[f][k] (32xK fp16)
// ---------------------------------------------------------------------------
__global__ __launch_bounds__(256) void k_castW(const float* __restrict__ W,
                                               _Float16* __restrict__ Wt,
                                               int K) {
  for (int i = threadIdx.x; i < K * 32; i += 256) {
    int k = i >> 5, f = i & 31;
    Wt[f * K + k] = (_Float16)W[i];
  }
}

// ---------------------------------------------------------------------------
// k_feat1: H = x @ W1 (f32 input read directly, cast to fp16 in-register),
// mfma_f32_16x16x32_f16, fused as_/ad_ scores. One wave = 16 nodes.
// ---------------------------------------------------------------------------
__global__ __launch_bounds__(256) void k_feat1(
    const float* __restrict__ x, const _Float16* __restrict__ Wt,
    const float* __restrict__ a_src, const float* __restrict__ a_dst,
    _Float16* __restrict__ Hh, float* __restrict__ as_, float* __restrict__ ad_,
    int N) {
  int w = threadIdx.x >> 6;
  int lane = threadIdx.x & 63;
  int base = (blockIdx.x * 4 + w) * 16;
  if (base >= N) return;
  int row16 = lane & 15;
  int kg = lane >> 4;  // 0..3
  f32x4 acc0 = {0.f, 0.f, 0.f, 0.f};
  f32x4 acc1 = {0.f, 0.f, 0.f, 0.f};
  const float* xr = x + (size_t)(base + row16) * 128 + kg * 8;
#pragma unroll
  for (int kt = 0; kt < 4; ++kt) {
    float4 u0 = *reinterpret_cast<const float4*>(xr + kt * 32);
    float4 u1 = *reinterpret_cast<const float4*>(xr + kt * 32 + 4);
    half8 a;
    a[0] = (_Float16)u0.x; a[1] = (_Float16)u0.y;
    a[2] = (_Float16)u0.z; a[3] = (_Float16)u0.w;
    a[4] = (_Float16)u1.x; a[5] = (_Float16)u1.y;
    a[6] = (_Float16)u1.z; a[7] = (_Float16)u1.w;
    half8 b0 = *reinterpret_cast<const half8*>(Wt + (size_t)row16 * 128 +
                                               kt * 32 + kg * 8);
    half8 b1 = *reinterpret_cast<const half8*>(Wt + (size_t)(16 + row16) * 128 +
                                               kt * 32 + kg * 8);
    acc0 = __builtin_amdgcn_mfma_f32_16x16x32_f16(a, b0, acc0, 0, 0, 0);
    acc1 = __builtin_amdgcn_mfma_f32_16x16x32_f16(a, b1, acc1, 0, 0, 0);
  }
  float aS0 = a_src[row16], aS1 = a_src[16 + row16];
  float aD0 = a_dst[row16], aD1 = a_dst[16 + row16];
  float tS[4], tD[4];
#pragma unroll
  for (int r = 0; r < 4; ++r) {
    int row = base + kg * 4 + r;
    Hh[(size_t)row * 32 + row16] = (_Float16)acc0[r];
    Hh[(size_t)row * 32 + 16 + row16] = (_Float16)acc1[r];
    tS[r] = acc0[r] * aS0 + acc1[r] * aS1;
    tD[r] = acc0[r] * aD0 + acc1[r] * aD1;
  }
#pragma unroll
  for (int off = 1; off <= 8; off <<= 1) {
#pragma unroll
    for (int r = 0; r < 4; ++r) {
      tS[r] += __shfl_xor(tS[r], off, 64);
      tD[r] += __shfl_xor(tD[r], off, 64);
    }
  }
  if (row16 == 0) {
#pragma unroll
    for (int r = 0; r < 4; ++r) {
      as_[base + kg * 4 + r] = tS[r];
      ad_[base + kg * 4 + r] = tD[r];
    }
  }
}

// ---------------------------------------------------------------------------
// CSR build: single-pass bucketed counting sort (R16 structure).
// ---------------------------------------------------------------------------
__global__ __launch_bounds__(256) void k_zero(int* __restrict__ p, int n) {
  int i = blockIdx.x * 256 + threadIdx.x;
  if (i < n) p[i] = 0;
}

__global__ __launch_bounds__(256) void k_bhist(const int* __restrict__ ei,
                                               int E, int* __restrict__ bcnt,
                                               int* __restrict__ hmatT,
                                               int nb, int nbuck) {
  __shared__ int h[MAXBUCK];
  for (int i = threadIdx.x; i < nbuck; i += 256) h[i] = 0;
  __syncthreads();
  long base = (long)blockIdx.x * EPB;
#pragma unroll 4
  for (int i = 0; i < EPB / 256; ++i) {
    long e = base + i * 256 + threadIdx.x;
    if (e < E) atomicAdd(&h[ei[E + e] >> BK_SH], 1);
  }
  __syncthreads();
  for (int i = threadIdx.x; i < nbuck; i += 256) {
    hmatT[(size_t)i * nb + blockIdx.x] = h[i];
    if (h[i]) atomicAdd(&bcnt[i], h[i]);
  }
}

__global__ __launch_bounds__(1024) void k_scan(const int* __restrict__ bcnt,
                                               int* __restrict__ boff,
                                               int* __restrict__ ptr, int nbuck,
                                               int N, int E) {
  __shared__ int s[1024];
  int t = threadIdx.x;
  int v = (t < nbuck) ? bcnt[t] : 0;
  s[t] = v;
  __syncthreads();
  for (int off = 1; off < 1024; off <<= 1) {
    int x = (t >= off) ? s[t - off] : 0;
    __syncthreads();
    s[t] += x;
    __syncthreads();
  }
  if (t < nbuck) boff[t] = s[t] - v;
  if (t == 0) {
    boff[nbuck] = E;
    ptr[N] = E;
  }
}

// one wave per bucket: prefix-scan that bucket's per-block counts (contiguous)
__global__ __launch_bounds__(256) void k_colscan(const int* __restrict__ hmatT,
                                                 int* __restrict__ lbgT,
                                                 const int* __restrict__ boff,
                                                 int nb, int nbuck) {
  int wid = (blockIdx.x * 256 + threadIdx.x) >> 6;  // bucket
  int lane = threadIdx.x & 63;
  if (wid >= nbuck) return;
  const int* row = hmatT + (size_t)wid * nb;
  int* orow = lbgT + (size_t)wid * nb;
  int base = boff[wid];
  for (int c = 0; c < nb; c += 64) {
    int v = (c + lane < nb) ? row[c + lane] : 0;
    int s = v;
#pragma unroll
    for (int off = 1; off < 64; off <<= 1) {
      int x = __shfl_up(s, off, 64);
      if (lane >= off) s += x;
    }
    if (c + lane < nb) orow[c + lane] = base + s - v;
    base += __shfl(s, 63, 64);
  }
}

// phase A: single-pass LDS-staged binning with bucket-sorted coalesced flush.
__global__ __launch_bounds__(256) void k_binA(
    const int* __restrict__ ei, int E, const int* __restrict__ hmatT,
    const int* __restrict__ lbgT, unsigned* __restrict__ packed, int nb,
    int nbuck) {
  __shared__ int h[MAXBUCK];
  __shared__ int lbase[MAXBUCK];
  __shared__ int lb[MAXBUCK];
  __shared__ int cur[MAXBUCK];
  __shared__ int psum[256];
  __shared__ unsigned rec[EPB];
  __shared__ unsigned char bkt[EPB];
  int t = threadIdx.x;
  for (int i = t; i < MAXBUCK; i += 256) {
    h[i] = (i < nbuck) ? hmatT[(size_t)i * nb + blockIdx.x] : 0;
    lbase[i] = (i < nbuck) ? lbgT[(size_t)i * nb + blockIdx.x] : 0;
  }
  __syncthreads();
  long base = (long)blockIdx.x * EPB;
  int cnt = (int)((E - base) < EPB ? (E - base) : EPB);
  int a0 = h[2 * t], a1 = h[2 * t + 1];
  psum[t] = a0 + a1;
  __syncthreads();
  for (int off = 1; off < 256; off <<= 1) {
    int x = (t >= off) ? psum[t - off] : 0;
    __syncthreads();
    psum[t] += x;
    __syncthreads();
  }
  int pex = psum[t] - (a0 + a1);
  lb[2 * t] = pex;
  lb[2 * t + 1] = pex + a0;
  cur[2 * t] = pex;
  cur[2 * t + 1] = pex + a0;
  __syncthreads();
#pragma unroll 4
  for (int i = 0; i < EPB / 256; ++i) {
    int e = i * 256 + t;
    if (e < cnt) {
      int s = ei[base + e], d = ei[E + base + e];
      int b = d >> BK_SH;
      int pos = atomicAdd(&cur[b], 1);
      rec[pos] = ((unsigned)s << 8) | (unsigned)(d & (BK_SZ - 1));
      bkt[pos] = (unsigned char)b;
    }
  }
  __syncthreads();
  for (int i = t; i < cnt; i += 256) {
    int b0 = bkt[i];
    int b = (i >= lb[b0] && i < cur[b0]) ? b0 : b0 + 256;
    packed[(size_t)lbase[b] + (i - lb[b])] = rec[i];
  }
}

// phase B: one block per bucket; node-level CSR ptr via LDS hist+scan.
__global__ __launch_bounds__(256) void k_binB(const unsigned* __restrict__ packed,
                                              const int* __restrict__ boff,
                                              int* __restrict__ ptr,
                                              int* __restrict__ srcs, int N) {
  int b = blockIdx.x;
  int beg = boff[b], end = boff[b + 1];
  int t = threadIdx.x;
  __shared__ int lcnt[BK_SZ];
  __shared__ int sc[BK_SZ];
  __shared__ int lcur[BK_SZ];
  lcnt[t] = 0;
  __syncthreads();
  for (int i = beg + t; i < end; i += 256)
    atomicAdd(&lcnt[packed[i] & (BK_SZ - 1)], 1);
  __syncthreads();
  int v = lcnt[t];
  sc[t] = v;
  __syncthreads();
  for (int off = 1; off < 256; off <<= 1) {
    int x = (t >= off) ? sc[t - off] : 0;
    __syncthreads();
    sc[t] += x;
    __syncthreads();
  }
  int excl = sc[t] - v;
  int node = (b << BK_SH) + t;
  if (node < N) ptr[node] = beg + excl;
  lcur[t] = excl;
  __syncthreads();
  for (int i = beg + t; i < end; i += 256) {
    unsigned p = packed[i];
    int slot = atomicAdd(&lcur[p & (BK_SZ - 1)], 1);
    srcs[(size_t)beg + slot] = (int)(p >> 8);
  }
}

// ---------------------------------------------------------------------------
// k_gatherT: 32 lanes/node = 8 edge-slots x 4 feature-lanes (half8 = 16B).
// Edge-PAIR inner loop using v_dot2_f32_f16: one VALU op covers 2 edges x 1
// feature with f32 accumulation. 1-deep pair prefetch (16 edges in flight).
// MODE=0: fused layer-2 feature transform: Hh2 = relu(row)@W2 (+as2/ad2)
// MODE=1: out(f32) = relu(row) @ Wf + bf   (fused final linear)
// ---------------------------------------------------------------------------
template <int MODE>
__global__ __launch_bounds__(256) void k_gatherT(
    const int* __restrict__ ptr, const int* __restrict__ srcs,
    const _Float16* __restrict__ Hh, const float* __restrict__ as_,
    const float* __restrict__ ad_, const float* __restrict__ b,
    const float* __restrict__ Wx, const float* __restrict__ aS2p,
    const float* __restrict__ aD2p, const float* __restrict__ bfp,
    _Float16* __restrict__ Hh2, float* __restrict__ as2v,
    float* __restrict__ ad2v, float* __restrict__ OUT, int N) {
  __shared__ float sW[32 * 32];
  __shared__ float sO[8][33];
  for (int i = threadIdx.x; i < 32 * 32; i += 256) sW[i] = Wx[i];
  int g = threadIdx.x >> 5;
  int lane = threadIdx.x & 31;
  int sub = lane >> 2;  // edge slot 0..7
  int q = lane & 3;     // feature block of 8
  int d = blockIdx.x * 8 + g;
  int dc = d < N ? d : N - 1;
  float ad_d = ad_[dc];
  float acc[8] = {0.f, 0.f, 0.f, 0.f, 0.f, 0.f, 0.f, 0.f};
  float sumw = 0.f;
  int beg = ptr[dc], end = ptr[dc + 1];
  const _Float16* Hq = Hh + q * 8;

  // pair-state: batches A (jb+sub) and B (jb+8+sub)
  bool vA0, vB0, vA1, vB1;
  int sA0, sB0, sA1, sB1;
  float aA0, aB0, aA1, aB1;
  half8 hA0, hB0, hA1, hB1;

  // prefetch pair 0 (jb=beg) and pair 1 (jb=beg+16)
  vA0 = beg + sub < end;          vB0 = beg + 8 + sub < end;
  sA0 = vA0 ? srcs[beg + sub] : dc;
  sB0 = vB0 ? srcs[beg + 8 + sub] : dc;
  aA0 = as_[sA0]; aB0 = as_[sB0];
  hA0 = *reinterpret_cast<const half8*>(Hq + (size_t)sA0 * 32);
  hB0 = *reinterpret_cast<const half8*>(Hq + (size_t)sB0 * 32);
  vA1 = beg + 16 + sub < end;     vB1 = beg + 24 + sub < end;
  sA1 = vA1 ? srcs[beg + 16 + sub] : dc;
  sB1 = vB1 ? srcs[beg + 24 + sub] : dc;
  aA1 = as_[sA1]; aB1 = as_[sB1];
  hA1 = *reinterpret_cast<const half8*>(Hq + (size_t)sA1 * 32);
  hB1 = *reinterpret_cast<const half8*>(Hq + (size_t)sB1 * 32);

  int nit = (end - beg + 15) >> 4;
  int jb = beg;
  for (int it = 0; it < nit; ++it) {
    // prefetch pair n+2
    int jn = jb + 32;
    bool vA2 = jn + sub < end, vB2 = jn + 8 + sub < end;
    int sA2 = vA2 ? srcs[jn + sub] : dc;
    int sB2 = vB2 ? srcs[jn + 8 + sub] : dc;
    float aA2 = as_[sA2], aB2 = as_[sB2];
    half8 hA2 = *reinterpret_cast<const half8*>(Hq + (size_t)sA2 * 32);
    half8 hB2 = *reinterpret_cast<const half8*>(Hq + (size_t)sB2 * 32);
    // consume pair n
    float scA = aA0 + ad_d, scB = aB0 + ad_d;
    float elA = scA > 0.f ? scA : NEG_SLOPE * scA;
    float elB = scB > 0.f ? scB : NEG_SLOPE * scB;
    float wA = vA0 ? __expf(elA) : 0.f;
    float wB = vB0 ? __expf(elB) : 0.f;
    auto pk = __builtin_amdgcn_cvt_pkrtz(wA, wB);
    h2 wpk = __builtin_bit_cast(h2, pk);
#pragma unroll
    for (int i = 0; i < 8; ++i) {
      h2 hp;
      hp[0] = hA0[i];
      hp[1] = hB0[i];
      acc[i] = __builtin_amdgcn_fdot2(wpk, hp, acc[i], false);
    }
    sumw += wA + wB;
    // rotate
    jb += 16;
    vA0 = vA1; vB0 = vB1; sA0 = sA1; sB0 = sB1;
    aA0 = aA1; aB0 = aB1; hA0 = hA1; hB0 = hB1;
    vA1 = vA2; vB1 = vB2; sA1 = sA2; sB1 = sB2;
    aA1 = aA2; aB1 = aB2; hA1 = hA2; hB1 = hB2;
  }
#pragma unroll
  for (int off = 4; off <= 16; off <<= 1) {
#pragma unroll
    for (int i = 0; i < 8; ++i) acc[i] += __shfl_xor(acc[i], off, 32);
    sumw += __shfl_xor(sumw, off, 32);
  }
  if (sub == 0) {
    // self-loop
    float s0 = as_[dc] + ad_d;
    float e0 = s0 > 0.f ? s0 : NEG_SLOPE * s0;
    float w0 = __expf(e0);
    half8 hs = *reinterpret_cast<const half8*>(Hq + (size_t)dc * 32);
#pragma unroll
    for (int i = 0; i < 8; ++i) acc[i] += w0 * (float)hs[i];
    sumw += w0;
    float inv = 1.f / (sumw + 1e-16f);
#pragma unroll
    for (int i = 0; i < 8; ++i)
      sO[g][q * 8 + i] = fmaxf(acc[i] * inv + b[q * 8 + i], 0.f);
  }
  __syncthreads();
  // epilogue GEMM: row (LDS) @ Wx -> 32 outputs per group
  float accf = (MODE == 1) ? bfp[lane] : 0.f;
#pragma unroll
  for (int k = 0; k < 32; ++k) accf += sO[g][k] * sW[k * 32 + lane];
  if (MODE == 1) {
    if (d < N) OUT[(size_t)d * 32 + lane] = accf;
  } else {
    if (d < N) Hh2[(size_t)d * 32 + lane] = (_Float16)accf;
    float vs = accf * aS2p[lane];
    float vd = accf * aD2p[lane];
#pragma unroll
    for (int off = 1; off < 32; off <<= 1) {
      vs += __shfl_xor(vs, off, 32);
      vd += __shfl_xor(vd, off, 32);
    }
    if (lane == 0 && d < N) {
      as2v[d] = vs;
      ad2v[d] = vd;
    }
  }
}

extern "C" void kernel_launch(void* const* d_in, const int* in_sizes, int n_in,
                              void* d_out, int out_size, void* d_ws,
                              size_t ws_size, hipStream_t stream) {
  const float* x = (const float*)d_in[0];
  const int* ei = (const int*)d_in[1];
  const float* W1 = (const float*)d_in[2];
  const float* as1 = (const float*)d_in[3];
  const float* ad1 = (const float*)d_in[4];
  const float* b1 = (const float*)d_in[5];
  const float* W2 = (const float*)d_in[6];
  const float* as2 = (const float*)d_in[7];
  const float* ad2 = (const float*)d_in[8];
  const float* b2 = (const float*)d_in[9];
  const float* Wf = (const float*)d_in[10];
  const float* bf = (const float*)d_in[11];
  float* out = (float*)d_out;

  const int H = in_sizes[3];        // 32
  const int FIN = in_sizes[2] / H;  // 128
  const int N = in_sizes[0] / FIN;  // 100000
  const int E = in_sizes[1] / 2;    // 3200000
  const int nbuck = (N + BK_SZ - 1) >> BK_SH;  // 391
  (void)n_in; (void)out_size; (void)ws_size; (void)H;

  const int nodeBlocks = (N + 7) / 8;
  const int binBlocks = (E + EPB - 1) / EPB;
  const int mfmaBlocks = (N / 16 + 3) / 4;

  char* basep = (char*)d_ws;
  unsigned* packed = (unsigned*)basep;  // E*4, dead after binB
  char* p = basep + (size_t)E * 4;
  _Float16* Hh1 = (_Float16*)p;  p += (size_t)N * 32 * 2;
  _Float16* Hh2 = (_Float16*)p;  p += (size_t)N * 32 * 2;
  _Float16* Wt1 = (_Float16*)p;  p += (size_t)128 * 32 * 2;
  float* asv = (float*)p;        p += (size_t)N * 4;
  float* adv = (float*)p;        p += (size_t)N * 4;
  float* asv2 = (float*)p;       p += (size_t)N * 4;
  float* adv2 = (float*)p;       p += (size_t)N * 4;
  int* ptr = (int*)p;            p += (size_t)(N + 1) * 4;
  int* srcs = (int*)p;           p += (size_t)E * 4;
  int* bcnt = (int*)p;           p += (size_t)nbuck * 4;
  int* boff = (int*)p;           p += (size_t)(nbuck + 1) * 4;
  int* hmatT = (int*)p;          p += (size_t)binBlocks * nbuck * 4;
  int* lbgT = (int*)p;

  // ---- build CSR by destination (once; graph is layer-invariant) ----
  k_zero<<<(nbuck + 255) / 256, 256, 0, stream>>>(bcnt, nbuck);
  k_bhist<<<binBlocks, 256, 0, stream>>>(ei, E, bcnt, hmatT, binBlocks, nbuck);
  k_scan<<<1, 1024, 0, stream>>>(bcnt, boff, ptr, nbuck, N, E);
  k_colscan<<<(nbuck * 64 + 255) / 256, 256, 0, stream>>>(hmatT, lbgT, boff,
                                                          binBlocks, nbuck);
  k_binA<<<binBlocks, 256, 0, stream>>>(ei, E, hmatT, lbgT, packed, binBlocks,
                                        nbuck);
  k_binB<<<nbuck, 256, 0, stream>>>(packed, boff, ptr, srcs, N);

  // ---- weights ----
  k_castW<<<1, 256, 0, stream>>>(W1, Wt1, 128);

  // ---- layer 1 (gather fuses layer-2 feature transform) ----
  k_feat1<<<mfmaBlocks, 256, 0, stream>>>(x, Wt1, as1, ad1, Hh1, asv, adv, N);
  k_gatherT<0><<<nodeBlocks, 256, 0, stream>>>(ptr, srcs, Hh1, asv, adv, b1,
                                               W2, as2, ad2, nullptr, Hh2,
                                               asv2, adv2, nullptr, N);

  // ---- layer 2 (final linear fused into gather) ----
  k_gatherT<1><<<nodeBlocks, 256, 0, stream>>>(ptr, srcs, Hh2, asv2, adv2, b2,
                                               Wf, nullptr, nullptr, bf,
                                               nullptr, nullptr, nullptr, out,
                                               N);
}